// Round 15
// baseline (186.047 us; speedup 1.0000x reference)
//
#include <hip/hip_runtime.h>
#include <math.h>

#define NPTS 2048
#define QQ 8
#define LAT 64
#define LOG2E 1.4426950408889634f
#define SQRT_LOG2E 1.2011224087864498f
#define LN2 0.6931471805599453f
#define FSTRIDE (QQ * NPTS)

typedef float v2f __attribute__((ext_vector_type(2)));

__device__ __forceinline__ float exp2_fast(float v) { return __builtin_amdgcn_exp2f(v); }
__device__ __forceinline__ float log2_fast(float v) { return __builtin_amdgcn_logf(v); }

__device__ __forceinline__ float softplus_f(float v) {
    return fmaxf(v, 0.f) + LN2 * log2_fast(1.f + exp2_fast(-fabsf(v) * LOG2E));
}

// ===== DECOMPOSITION ROUND =====
// feat: body repeated 32x (idempotent stores; asm barriers prevent CSE/hoist)
// pair: R11-exact REPS=8 (known 72.4us).
// Yields: feat_pass, OH = total - feat32_dur - pair8_dur, both kernels' PMC.
#define REP_F 32
#define REPS 8

__global__ __launch_bounds__(256) void feat_kernel(
    const float* __restrict__ x, const float* __restrict__ y,
    const float* __restrict__ W1, const float* __restrict__ b1,
    const float* __restrict__ Ww, const float* __restrict__ bw,
    const float* __restrict__ Wf, const float* __restrict__ bf,
    const float* __restrict__ Ws, const float* __restrict__ bs,
    float* __restrict__ FX, float* __restrict__ FY)
{
    const int t    = threadIdx.x;
    const int wv   = t >> 6;
    const int lane = t & 63;
    const int c    = lane & 7;
    const int q    = lane >> 3;
    const int bid  = blockIdx.x;
    const int side = bid >> 9;
    const int i    = (bid & 511) * 4 + wv;
    const float* P = side ? y : x;
    float* F = side ? FY : FX;

    const float p0_ = P[i*3+0], p1_ = P[i*3+1], p2_ = P[i*3+2];
    const float lam = 1.0507009873554805f, lamalf = 1.7580993408473766f;

    #pragma unroll 1
    for (int rep = 0; rep < REP_F; ++rep) {
        // Anti-collapse: compiler must assume these change every rep.
        int szero = 0;
        asm volatile("" : "+s"(szero));
        float p0 = p0_, p1 = p1_, p2 = p2_;
        asm volatile("" : "+v"(p0), "+v"(p1), "+v"(p2));
        const float* W1r = W1 + szero;
        const float* Wwr = Ww + szero;
        const float* Wsr = Ws + szero;
        const float* Wfr = Wf + szero;

        float wa = 0.f, sa = 0.f, f0a = 0.f, f1a = 0.f, f2a = 0.f;
        #pragma unroll
        for (int it = 0; it < 8; ++it) {
            int l = it*8 + c;
            float v = fmaf(W1r[l*3+0], p0, fmaf(W1r[l*3+1], p1, fmaf(W1r[l*3+2], p2, b1[l])));
            float e = exp2_fast(v * LOG2E);
            float h = v > 0.f ? lam * v : lamalf * (e - 1.f);
            wa  = fmaf(Wwr[q*LAT + l],       h, wa);
            sa  = fmaf(Wsr[q*LAT + l],       h, sa);
            f0a = fmaf(Wfr[(q*3+0)*LAT + l], h, f0a);
            f1a = fmaf(Wfr[(q*3+1)*LAT + l], h, f1a);
            f2a = fmaf(Wfr[(q*3+2)*LAT + l], h, f2a);
        }
        #pragma unroll
        for (int m = 1; m <= 4; m <<= 1) {
            wa  += __shfl_xor(wa,  m, 64);
            sa  += __shfl_xor(sa,  m, 64);
            f0a += __shfl_xor(f0a, m, 64);
            f1a += __shfl_xor(f1a, m, 64);
            f2a += __shfl_xor(f2a, m, 64);
        }
        float w  = softplus_f(wa  + bw[q]);
        float s  = softplus_f(sa  + bs[q]);
        float f0 = softplus_f(f0a + bf[q*3+0]);
        float f1 = softplus_f(f1a + bf[q*3+1]);
        float f2 = softplus_f(f2a + bf[q*3+2]);
        float phase = f0*p0 + f1*p1 + f2*p2;
        float fr = phase - floorf(phase);
        float sn = __builtin_amdgcn_sinf(fr);
        float cs = __builtin_amdgcn_cosf(fr);
        float a  = w * 1.1892071150027210f * sqrtf(s);
        if (c == 0) {
            F[0*FSTRIDE + q*NPTS + i] = a * cs;
            F[1*FSTRIDE + q*NPTS + i] = a * sn;
            F[2*FSTRIDE + q*NPTS + i] = s * s;
        }
    }
}

// pair: R11-exact (REPS=8, launch_bounds(256,8)) to replicate the 72.4us row.
__global__ __launch_bounds__(256, 8) void pair_kernel(
    const float* __restrict__ x, const float* __restrict__ y,
    const float* __restrict__ FX, const float* __restrict__ FY,
    float* __restrict__ K)
{
    __shared__ float lfi[3][QQ][32];
    __shared__ float lfj[3][QQ][64];
    __shared__ float lpi[3][32];
    __shared__ float lpj[3][64];

    const int t  = threadIdx.x;
    const int tx = t & 31;
    const int ty = t >> 5;
    const int i0 = blockIdx.y * 32, j0 = blockIdx.x * 64;

    #pragma unroll
    for (int k = 0; k < 3; ++k) {
        int idx = t + k * 256;
        int f = idx >> 8, rem = idx & 255, q = rem >> 5, ii = rem & 31;
        lfi[f][q][ii] = FX[f*FSTRIDE + q*NPTS + i0 + ii];
    }
    #pragma unroll
    for (int k = 0; k < 6; ++k) {
        int idx = t + k * 256;
        int f = idx >> 9, q = (idx >> 6) & 7, jj = idx & 63;
        lfj[f][q][jj] = FY[f*FSTRIDE + q*NPTS + j0 + jj];
    }
    if (t < 96) {
        int d = t >> 5, ii = t & 31;
        lpi[d][ii] = x[(i0 + ii)*3 + d] * SQRT_LOG2E;
    }
    if (t < 192) {
        int d = t >> 6, jj = t & 63;
        lpj[d][jj] = y[(j0 + jj)*3 + d] * SQRT_LOG2E;
    }
    __syncthreads();

    v2f yj0 = *(const v2f*)&lpj[0][tx*2];
    v2f yj1 = *(const v2f*)&lpj[1][tx*2];
    v2f yj2 = *(const v2f*)&lpj[2][tx*2];
    float4 xi0 = *(const float4*)&lpi[0][ty*4];
    float4 xi1 = *(const float4*)&lpi[1][ty*4];
    float4 xi2 = *(const float4*)&lpi[2][ty*4];
    float xs0[4] = {xi0.x, xi0.y, xi0.z, xi0.w};
    float xs1[4] = {xi1.x, xi1.y, xi1.z, xi1.w};
    float xs2[4] = {xi2.x, xi2.y, xi2.z, xi2.w};

    v2f d2n[4];
    #pragma unroll
    for (int ii = 0; ii < 4; ++ii) {
        v2f dx = xs0[ii] - yj0;
        v2f dy = xs1[ii] - yj1;
        v2f dz = xs2[ii] - yj2;
        d2n[ii] = -(dx*dx + dy*dy + dz*dz);
    }

    v2f acc[4] = {};
    #pragma unroll 1
    for (int rep = 0; rep < REPS; ++rep) {
        #pragma unroll 1
        for (int q = 0; q < QQ; ++q) {
            float4 cai4 = *(const float4*)&lfi[0][q][ty*4];
            float4 sai4 = *(const float4*)&lfi[1][q][ty*4];
            float4 s2i4 = *(const float4*)&lfi[2][q][ty*4];
            v2f caj = *(const v2f*)&lfj[0][q][tx*2];
            v2f saj = *(const v2f*)&lfj[1][q][tx*2];
            v2f s2j = *(const v2f*)&lfj[2][q][tx*2];
            float cai[4] = {cai4.x, cai4.y, cai4.z, cai4.w};
            float sai[4] = {sai4.x, sai4.y, sai4.z, sai4.w};
            float s2i[4] = {s2i4.x, s2i4.y, s2i4.z, s2i4.w};
            #pragma unroll
            for (int ii = 0; ii < 4; ++ii) {
                v2f s2  = s2i[ii] + s2j;
                v2f inv = { __builtin_amdgcn_rcpf(s2.x), __builtin_amdgcn_rcpf(s2.y) };
                v2f tt  = d2n[ii] * inv;
                v2f e   = { exp2_fast(tt.x), exp2_fast(tt.y) };
                v2f ct  = cai[ii]*caj + sai[ii]*saj;
                acc[ii] += (inv * e) * ct;
            }
        }
    }

    #pragma unroll
    for (int ii = 0; ii < 4; ++ii) {
        int i = i0 + ty*4 + ii;
        float2 o = make_float2(acc[ii].x * (1.0f/REPS), acc[ii].y * (1.0f/REPS));
        *(float2*)&K[(size_t)i * NPTS + j0 + tx*2] = o;
    }
}

extern "C" void kernel_launch(void* const* d_in, const int* in_sizes, int n_in,
                              void* d_out, int out_size, void* d_ws, size_t ws_size,
                              hipStream_t stream) {
    const float* x  = (const float*)d_in[0];
    const float* y  = (const float*)d_in[1];
    const float* W1 = (const float*)d_in[2];
    const float* b1 = (const float*)d_in[3];
    const float* Ww = (const float*)d_in[4];
    const float* bw = (const float*)d_in[5];
    const float* Wf = (const float*)d_in[6];
    const float* bf = (const float*)d_in[7];
    const float* Ws = (const float*)d_in[8];
    const float* bs = (const float*)d_in[9];
    float* K = (float*)d_out;

    float* FX = (float*)d_ws;
    float* FY = FX + 3 * FSTRIDE;

    feat_kernel<<<1024, 256, 0, stream>>>(x, y, W1, b1, Ww, bw, Wf, bf, Ws, bs, FX, FY);

    dim3 grid(NPTS/64, NPTS/32);
    pair_kernel<<<grid, 256, 0, stream>>>(x, y, FX, FY, K);
}

// Round 16
// 22.344 us; speedup vs baseline: 8.3265x; 8.3265x over previous
//
#include <hip/hip_runtime.h>
#include <math.h>

#define NPTS 2048
#define QQ 8
#define LAT 64
#define LOG2E 1.4426950408889634f
#define SQRT_LOG2E 1.2011224087864498f
#define LN2 0.6931471805599453f
#define FSTRIDE (QQ * NPTS)

typedef float v2f __attribute__((ext_vector_type(2)));

__device__ __forceinline__ float exp2_fast(float v) { return __builtin_amdgcn_exp2f(v); }
__device__ __forceinline__ float log2_fast(float v) { return __builtin_amdgcn_logf(v); }

__device__ __forceinline__ float softplus_f(float v) {
    return fmaxf(v, 0.f) + LN2 * log2_fast(1.f + exp2_fast(-fabsf(v) * LOG2E));
}

// feat (R10, unchanged): one point per wave, no LDS, no barriers.
__global__ __launch_bounds__(256) void feat_kernel(
    const float* __restrict__ x, const float* __restrict__ y,
    const float* __restrict__ W1, const float* __restrict__ b1,
    const float* __restrict__ Ww, const float* __restrict__ bw,
    const float* __restrict__ Wf, const float* __restrict__ bf,
    const float* __restrict__ Ws, const float* __restrict__ bs,
    float* __restrict__ FX, float* __restrict__ FY)
{
    const int t    = threadIdx.x;
    const int wv   = t >> 6;
    const int lane = t & 63;
    const int c    = lane & 7;
    const int q    = lane >> 3;
    const int bid  = blockIdx.x;
    const int side = bid >> 9;
    const int i    = (bid & 511) * 4 + wv;
    const float* P = side ? y : x;
    float* F = side ? FY : FX;

    const float p0 = P[i*3+0], p1 = P[i*3+1], p2 = P[i*3+2];
    const float lam = 1.0507009873554805f, lamalf = 1.7580993408473766f;

    float wa = 0.f, sa = 0.f, f0a = 0.f, f1a = 0.f, f2a = 0.f;
    #pragma unroll
    for (int it = 0; it < 8; ++it) {
        int l = it*8 + c;
        float v = fmaf(W1[l*3+0], p0, fmaf(W1[l*3+1], p1, fmaf(W1[l*3+2], p2, b1[l])));
        float e = exp2_fast(v * LOG2E);
        float h = v > 0.f ? lam * v : lamalf * (e - 1.f);
        wa  = fmaf(Ww[q*LAT + l],       h, wa);
        sa  = fmaf(Ws[q*LAT + l],       h, sa);
        f0a = fmaf(Wf[(q*3+0)*LAT + l], h, f0a);
        f1a = fmaf(Wf[(q*3+1)*LAT + l], h, f1a);
        f2a = fmaf(Wf[(q*3+2)*LAT + l], h, f2a);
    }
    #pragma unroll
    for (int m = 1; m <= 4; m <<= 1) {
        wa  += __shfl_xor(wa,  m, 64);
        sa  += __shfl_xor(sa,  m, 64);
        f0a += __shfl_xor(f0a, m, 64);
        f1a += __shfl_xor(f1a, m, 64);
        f2a += __shfl_xor(f2a, m, 64);
    }
    float w  = softplus_f(wa  + bw[q]);
    float s  = softplus_f(sa  + bs[q]);
    float f0 = softplus_f(f0a + bf[q*3+0]);
    float f1 = softplus_f(f1a + bf[q*3+1]);
    float f2 = softplus_f(f2a + bf[q*3+2]);
    float phase = f0*p0 + f1*p1 + f2*p2;
    float fr = phase - floorf(phase);
    float sn = __builtin_amdgcn_sinf(fr);
    float cs = __builtin_amdgcn_cosf(fr);
    float a  = w * 1.1892071150027210f * sqrtf(s);
    if (c == 0) {
        F[0*FSTRIDE + q*NPTS + i] = a * cs;
        F[1*FSTRIDE + q*NPTS + i] = a * sn;
        F[2*FSTRIDE + q*NPTS + i] = s * s;
    }
}

// pair v7: TWO independent j-tiles per block, both staged up front, ONE
// barrier, no rotation. 1024 blocks (4/CU). Tile A's stores (non-temporal)
// drain under tile B's compute; i-stage + ramp amortize 2x. q-loop body is
// the proven R13 floor (6.97us/pass device-wide).
__global__ __launch_bounds__(256, 4) void pair_kernel(
    const float* __restrict__ x, const float* __restrict__ y,
    const float* __restrict__ FX, const float* __restrict__ FY,
    float* __restrict__ K)
{
    __shared__ float lfi[3][QQ][32];
    __shared__ float lpi[3][32];
    __shared__ float lfj[2][3][QQ][64];
    __shared__ float lpj[2][3][64];

    const int t  = threadIdx.x;
    const int tx = t & 31;
    const int ty = t >> 5;
    const int i0 = (blockIdx.x >> 4) * 32;
    const int jb = (blockIdx.x & 15) * 128;

    // ---- stage everything (i-side + both j-tiles), single barrier ----
    #pragma unroll
    for (int k = 0; k < 3; ++k) {
        int idx = t + k * 256;
        int f = idx >> 8, rem = idx & 255, q = rem >> 5, ii = rem & 31;
        lfi[f][q][ii] = FX[f*FSTRIDE + q*NPTS + i0 + ii];
    }
    #pragma unroll
    for (int k = 0; k < 6; ++k) {
        int idx = t + k * 256;
        int f = idx >> 9, q = (idx >> 6) & 7, jj = idx & 63;
        lfj[0][f][q][jj] = FY[f*FSTRIDE + q*NPTS + jb + jj];
        lfj[1][f][q][jj] = FY[f*FSTRIDE + q*NPTS + jb + 64 + jj];
    }
    if (t < 96) {
        int d = t >> 5, ii = t & 31;
        lpi[d][ii] = x[(i0 + ii)*3 + d] * SQRT_LOG2E;
    }
    if (t < 192) {
        int d = t >> 6, jj = t & 63;
        lpj[0][d][jj] = y[(jb + jj)*3 + d] * SQRT_LOG2E;
        lpj[1][d][jj] = y[(jb + 64 + jj)*3 + d] * SQRT_LOG2E;
    }
    __syncthreads();

    float4 xi0 = *(const float4*)&lpi[0][ty*4];
    float4 xi1 = *(const float4*)&lpi[1][ty*4];
    float4 xi2 = *(const float4*)&lpi[2][ty*4];
    float xs0[4] = {xi0.x, xi0.y, xi0.z, xi0.w};
    float xs1[4] = {xi1.x, xi1.y, xi1.z, xi1.w};
    float xs2[4] = {xi2.x, xi2.y, xi2.z, xi2.w};

    #pragma unroll 1
    for (int tile = 0; tile < 2; ++tile) {
        const int j0 = jb + tile * 64;

        v2f yj0 = *(const v2f*)&lpj[tile][0][tx*2];
        v2f yj1 = *(const v2f*)&lpj[tile][1][tx*2];
        v2f yj2 = *(const v2f*)&lpj[tile][2][tx*2];

        v2f d2n[4];
        #pragma unroll
        for (int ii = 0; ii < 4; ++ii) {
            v2f dx = xs0[ii] - yj0;
            v2f dy = xs1[ii] - yj1;
            v2f dz = xs2[ii] - yj2;
            d2n[ii] = -(dx*dx + dy*dy + dz*dz);
        }

        v2f acc[4] = {};
        #pragma unroll 1
        for (int q = 0; q < QQ; ++q) {
            float4 cai4 = *(const float4*)&lfi[0][q][ty*4];
            float4 sai4 = *(const float4*)&lfi[1][q][ty*4];
            float4 s2i4 = *(const float4*)&lfi[2][q][ty*4];
            v2f caj = *(const v2f*)&lfj[tile][0][q][tx*2];
            v2f saj = *(const v2f*)&lfj[tile][1][q][tx*2];
            v2f s2j = *(const v2f*)&lfj[tile][2][q][tx*2];
            float cai[4] = {cai4.x, cai4.y, cai4.z, cai4.w};
            float sai[4] = {sai4.x, sai4.y, sai4.z, sai4.w};
            float s2i[4] = {s2i4.x, s2i4.y, s2i4.z, s2i4.w};
            #pragma unroll
            for (int ii = 0; ii < 4; ++ii) {
                v2f s2  = s2i[ii] + s2j;
                v2f inv = { __builtin_amdgcn_rcpf(s2.x), __builtin_amdgcn_rcpf(s2.y) };
                v2f tt  = d2n[ii] * inv;
                v2f e   = { exp2_fast(tt.x), exp2_fast(tt.y) };
                v2f ct  = cai[ii]*caj + sai[ii]*saj;
                acc[ii] += (inv * e) * ct;
            }
        }

        // Non-temporal stores: output is write-once streaming; issue now,
        // drain under the next tile's compute.
        #pragma unroll
        for (int ii = 0; ii < 4; ++ii) {
            int i = i0 + ty*4 + ii;
            float2 o = make_float2(acc[ii].x, acc[ii].y);
            __builtin_nontemporal_store(*(const unsigned long long*)&o,
                (unsigned long long*)&K[(size_t)i * NPTS + j0 + tx*2]);
        }
    }
}

extern "C" void kernel_launch(void* const* d_in, const int* in_sizes, int n_in,
                              void* d_out, int out_size, void* d_ws, size_t ws_size,
                              hipStream_t stream) {
    const float* x  = (const float*)d_in[0];
    const float* y  = (const float*)d_in[1];
    const float* W1 = (const float*)d_in[2];
    const float* b1 = (const float*)d_in[3];
    const float* Ww = (const float*)d_in[4];
    const float* bw = (const float*)d_in[5];
    const float* Wf = (const float*)d_in[6];
    const float* bf = (const float*)d_in[7];
    const float* Ws = (const float*)d_in[8];
    const float* bs = (const float*)d_in[9];
    float* K = (float*)d_out;

    float* FX = (float*)d_ws;
    float* FY = FX + 3 * FSTRIDE;

    feat_kernel<<<1024, 256, 0, stream>>>(x, y, W1, b1, Ww, bw, Wf, bf, Ws, bs, FX, FY);

    pair_kernel<<<1024, 256, 0, stream>>>(x, y, FX, FY, K);
}

// Round 17
// 22.138 us; speedup vs baseline: 8.4038x; 1.0093x over previous
//
#include <hip/hip_runtime.h>
#include <math.h>

#define NPTS 2048
#define QQ 8
#define LAT 64
#define LOG2E 1.4426950408889634f
#define SQRT_LOG2E 1.2011224087864498f
#define LN2 0.6931471805599453f
#define FSTRIDE (QQ * NPTS)

typedef float v2f __attribute__((ext_vector_type(2)));

__device__ __forceinline__ float exp2_fast(float v) { return __builtin_amdgcn_exp2f(v); }
__device__ __forceinline__ float log2_fast(float v) { return __builtin_amdgcn_logf(v); }

__device__ __forceinline__ float softplus_f(float v) {
    return fmaxf(v, 0.f) + LN2 * log2_fast(1.f + exp2_fast(-fabsf(v) * LOG2E));
}

// feat (R10, unchanged): one point per wave, no LDS, no barriers.
__global__ __launch_bounds__(256) void feat_kernel(
    const float* __restrict__ x, const float* __restrict__ y,
    const float* __restrict__ W1, const float* __restrict__ b1,
    const float* __restrict__ Ww, const float* __restrict__ bw,
    const float* __restrict__ Wf, const float* __restrict__ bf,
    const float* __restrict__ Ws, const float* __restrict__ bs,
    float* __restrict__ FX, float* __restrict__ FY)
{
    const int t    = threadIdx.x;
    const int wv   = t >> 6;
    const int lane = t & 63;
    const int c    = lane & 7;
    const int q    = lane >> 3;
    const int bid  = blockIdx.x;
    const int side = bid >> 9;
    const int i    = (bid & 511) * 4 + wv;
    const float* P = side ? y : x;
    float* F = side ? FY : FX;

    const float p0 = P[i*3+0], p1 = P[i*3+1], p2 = P[i*3+2];
    const float lam = 1.0507009873554805f, lamalf = 1.7580993408473766f;

    float wa = 0.f, sa = 0.f, f0a = 0.f, f1a = 0.f, f2a = 0.f;
    #pragma unroll
    for (int it = 0; it < 8; ++it) {
        int l = it*8 + c;
        float v = fmaf(W1[l*3+0], p0, fmaf(W1[l*3+1], p1, fmaf(W1[l*3+2], p2, b1[l])));
        float e = exp2_fast(v * LOG2E);
        float h = v > 0.f ? lam * v : lamalf * (e - 1.f);
        wa  = fmaf(Ww[q*LAT + l],       h, wa);
        sa  = fmaf(Ws[q*LAT + l],       h, sa);
        f0a = fmaf(Wf[(q*3+0)*LAT + l], h, f0a);
        f1a = fmaf(Wf[(q*3+1)*LAT + l], h, f1a);
        f2a = fmaf(Wf[(q*3+2)*LAT + l], h, f2a);
    }
    #pragma unroll
    for (int m = 1; m <= 4; m <<= 1) {
        wa  += __shfl_xor(wa,  m, 64);
        sa  += __shfl_xor(sa,  m, 64);
        f0a += __shfl_xor(f0a, m, 64);
        f1a += __shfl_xor(f1a, m, 64);
        f2a += __shfl_xor(f2a, m, 64);
    }
    float w  = softplus_f(wa  + bw[q]);
    float s  = softplus_f(sa  + bs[q]);
    float f0 = softplus_f(f0a + bf[q*3+0]);
    float f1 = softplus_f(f1a + bf[q*3+1]);
    float f2 = softplus_f(f2a + bf[q*3+2]);
    float phase = f0*p0 + f1*p1 + f2*p2;
    float fr = phase - floorf(phase);
    float sn = __builtin_amdgcn_sinf(fr);
    float cs = __builtin_amdgcn_cosf(fr);
    float a  = w * 1.1892071150027210f * sqrtf(s);
    if (c == 0) {
        F[0*FSTRIDE + q*NPTS + i] = a * cs;
        F[1*FSTRIDE + q*NPTS + i] = a * sn;
        F[2*FSTRIDE + q*NPTS + i] = s * s;
    }
}

// pair v7: TWO independent j-tiles per block, both staged up front, ONE
// barrier, no rotation. 1024 blocks (4/CU). Tile A's stores (non-temporal)
// drain under tile B's compute; i-stage + ramp amortize 2x. q-loop body is
// the proven R13 floor (6.97us/pass device-wide).
__global__ __launch_bounds__(256, 4) void pair_kernel(
    const float* __restrict__ x, const float* __restrict__ y,
    const float* __restrict__ FX, const float* __restrict__ FY,
    float* __restrict__ K)
{
    __shared__ float lfi[3][QQ][32];
    __shared__ float lpi[3][32];
    __shared__ float lfj[2][3][QQ][64];
    __shared__ float lpj[2][3][64];

    const int t  = threadIdx.x;
    const int tx = t & 31;
    const int ty = t >> 5;
    const int i0 = (blockIdx.x >> 4) * 32;
    const int jb = (blockIdx.x & 15) * 128;

    // ---- stage everything (i-side + both j-tiles), single barrier ----
    #pragma unroll
    for (int k = 0; k < 3; ++k) {
        int idx = t + k * 256;
        int f = idx >> 8, rem = idx & 255, q = rem >> 5, ii = rem & 31;
        lfi[f][q][ii] = FX[f*FSTRIDE + q*NPTS + i0 + ii];
    }
    #pragma unroll
    for (int k = 0; k < 6; ++k) {
        int idx = t + k * 256;
        int f = idx >> 9, q = (idx >> 6) & 7, jj = idx & 63;
        lfj[0][f][q][jj] = FY[f*FSTRIDE + q*NPTS + jb + jj];
        lfj[1][f][q][jj] = FY[f*FSTRIDE + q*NPTS + jb + 64 + jj];
    }
    if (t < 96) {
        int d = t >> 5, ii = t & 31;
        lpi[d][ii] = x[(i0 + ii)*3 + d] * SQRT_LOG2E;
    }
    if (t < 192) {
        int d = t >> 6, jj = t & 63;
        lpj[0][d][jj] = y[(jb + jj)*3 + d] * SQRT_LOG2E;
        lpj[1][d][jj] = y[(jb + 64 + jj)*3 + d] * SQRT_LOG2E;
    }
    __syncthreads();

    float4 xi0 = *(const float4*)&lpi[0][ty*4];
    float4 xi1 = *(const float4*)&lpi[1][ty*4];
    float4 xi2 = *(const float4*)&lpi[2][ty*4];
    float xs0[4] = {xi0.x, xi0.y, xi0.z, xi0.w};
    float xs1[4] = {xi1.x, xi1.y, xi1.z, xi1.w};
    float xs2[4] = {xi2.x, xi2.y, xi2.z, xi2.w};

    #pragma unroll 1
    for (int tile = 0; tile < 2; ++tile) {
        const int j0 = jb + tile * 64;

        v2f yj0 = *(const v2f*)&lpj[tile][0][tx*2];
        v2f yj1 = *(const v2f*)&lpj[tile][1][tx*2];
        v2f yj2 = *(const v2f*)&lpj[tile][2][tx*2];

        v2f d2n[4];
        #pragma unroll
        for (int ii = 0; ii < 4; ++ii) {
            v2f dx = xs0[ii] - yj0;
            v2f dy = xs1[ii] - yj1;
            v2f dz = xs2[ii] - yj2;
            d2n[ii] = -(dx*dx + dy*dy + dz*dz);
        }

        v2f acc[4] = {};
        #pragma unroll 1
        for (int q = 0; q < QQ; ++q) {
            float4 cai4 = *(const float4*)&lfi[0][q][ty*4];
            float4 sai4 = *(const float4*)&lfi[1][q][ty*4];
            float4 s2i4 = *(const float4*)&lfi[2][q][ty*4];
            v2f caj = *(const v2f*)&lfj[tile][0][q][tx*2];
            v2f saj = *(const v2f*)&lfj[tile][1][q][tx*2];
            v2f s2j = *(const v2f*)&lfj[tile][2][q][tx*2];
            float cai[4] = {cai4.x, cai4.y, cai4.z, cai4.w};
            float sai[4] = {sai4.x, sai4.y, sai4.z, sai4.w};
            float s2i[4] = {s2i4.x, s2i4.y, s2i4.z, s2i4.w};
            #pragma unroll
            for (int ii = 0; ii < 4; ++ii) {
                v2f s2  = s2i[ii] + s2j;
                v2f inv = { __builtin_amdgcn_rcpf(s2.x), __builtin_amdgcn_rcpf(s2.y) };
                v2f tt  = d2n[ii] * inv;
                v2f e   = { exp2_fast(tt.x), exp2_fast(tt.y) };
                v2f ct  = cai[ii]*caj + sai[ii]*saj;
                acc[ii] += (inv * e) * ct;
            }
        }

        // Non-temporal stores: output is write-once streaming; issue now,
        // drain under the next tile's compute.
        #pragma unroll
        for (int ii = 0; ii < 4; ++ii) {
            int i = i0 + ty*4 + ii;
            float2 o = make_float2(acc[ii].x, acc[ii].y);
            __builtin_nontemporal_store(*(const unsigned long long*)&o,
                (unsigned long long*)&K[(size_t)i * NPTS + j0 + tx*2]);
        }
    }
}

extern "C" void kernel_launch(void* const* d_in, const int* in_sizes, int n_in,
                              void* d_out, int out_size, void* d_ws, size_t ws_size,
                              hipStream_t stream) {
    const float* x  = (const float*)d_in[0];
    const float* y  = (const float*)d_in[1];
    const float* W1 = (const float*)d_in[2];
    const float* b1 = (const float*)d_in[3];
    const float* Ww = (const float*)d_in[4];
    const float* bw = (const float*)d_in[5];
    const float* Wf = (const float*)d_in[6];
    const float* bf = (const float*)d_in[7];
    const float* Ws = (const float*)d_in[8];
    const float* bs = (const float*)d_in[9];
    float* K = (float*)d_out;

    float* FX = (float*)d_ws;
    float* FY = FX + 3 * FSTRIDE;

    feat_kernel<<<1024, 256, 0, stream>>>(x, y, W1, b1, Ww, bw, Wf, bf, Ws, bs, FX, FY);

    pair_kernel<<<1024, 256, 0, stream>>>(x, y, FX, FY, K);
}